// Round 7
// baseline (87.510 us; speedup 1.0000x reference)
//
#include <hip/hip_runtime.h>
#include <stdint.h>

typedef __attribute__((ext_vector_type(8))) short s16x8;
typedef __attribute__((ext_vector_type(4))) float f32x4;

__device__ __forceinline__ short f2bf(float f){
  union { float f; uint32_t u; } v; v.f = f;
  uint32_t u = v.u;
  u += 0x7fffu + ((u >> 16) & 1u);
  return (short)(u >> 16);
}
__device__ __forceinline__ float sigm_fast(float x){
  float e = __builtin_amdgcn_exp2f(x * -1.44269504f);
  return __builtin_amdgcn_rcpf(1.f + e);
}
__device__ __forceinline__ float tanh_fast(float x){
  float e = __builtin_amdgcn_exp2f(x * 2.88539008f);
  return __builtin_fmaf(-2.f, __builtin_amdgcn_rcpf(e + 1.f), 1.f);
}

#define MFMA16(a, b, c) __builtin_amdgcn_mfma_f32_16x16x32_bf16((a), (b), (c), 0, 0, 0)

// Fused TemporalEncoder. Round-7 structure: DUAL-STREAM block. M=32 seqs as two
// independent 16-seq streams S0/S1 in ONE 4-wave block, grid=256 (1 block/CU).
// Rationale (round-6 counters): 2-blocks/CU never hid each other's stalls
// (~1000 cyc/step exposed); instead each wave now interleaves two streams --
// S1 MFMAs issue under S0 MFMA latency, S0 transcendental chain (VALU pipe)
// issues under S1 MFMAs (matrix pipe), weights/bias regs shared across streams,
// barrier amortized over 2x work. 1 wave/SIMD: ILP replaces TLP.
__global__ __launch_bounds__(256, 1) void te_fused(
    const float* __restrict__ x,
    const float* __restrict__ w1, const float* __restrict__ b1,
    const float* __restrict__ w2, const float* __restrict__ b2,
    const float* __restrict__ Wih, const float* __restrict__ Whh,
    const float* __restrict__ bih, const float* __restrict__ bhh,
    float* __restrict__ out)
{
  constexpr int T = 100;
  __shared__ float x_s[32 * T];             // 32 staged input rows
  __shared__ short hA[2][2][16 * 72];       // [stream][buf][seq][72-pad dim]
  __shared__ short ring[2][4][16 * 24];     // [stream][slot=tau%4][seq][24-pad ch]
  __shared__ short s_s[2][2][16 * 40];      // [stream][buf][seq][40-pad ch(32)]

  const int tid  = threadIdx.x;
  const int lane = tid & 63;
  const int wv   = tid >> 6;
  const int l15  = lane & 15;
  const int lg   = lane >> 4;
  const int seq0 = blockIdx.x * 32;

  // ---- stage x (32*100 floats, contiguous) ----
  {
    const float4* gx = reinterpret_cast<const float4*>(x + (size_t)seq0 * T);
    float4* sx = reinterpret_cast<float4*>(x_s);
    for (int i = tid; i < (32 * T) / 4; i += 256) sx[i] = gx[i];
  }
  // zero h buf0 (both streams) and both rings
  {
    int* p = reinterpret_cast<int*>(&hA[0][0][0]);   // hA[0][0] and hA[1][0]:
    for (int i = tid; i < (16 * 72) / 2; i += 256) p[i] = 0;
    int* p1 = reinterpret_cast<int*>(&hA[1][0][0]);
    for (int i = tid; i < (16 * 72) / 2; i += 256) p1[i] = 0;
    int* q = reinterpret_cast<int*>(&ring[0][0][0]); // both rings contiguous
    for (int i = tid; i < (2 * 4 * 16 * 24) / 2; i += 256) q[i] = 0;
  }

  // ---- weight B-fragments (shared by both streams) ----
  s16x8 WhhHi[3][2], WihHi[3];
  f32x4 bias_r, bias_z, bias_xn, bias_hn;
#pragma unroll
  for (int g = 0; g < 3; ++g) {
    const int n = 64 * g + 16 * wv + l15;
#pragma unroll
    for (int ks = 0; ks < 2; ++ks) {
      const float* p = Whh + n * 64 + ks * 32 + lg * 8;
#pragma unroll
      for (int j = 0; j < 8; ++j) WhhHi[g][ks][j] = f2bf(p[j]);
    }
    const float* q = Wih + n * 32 + lg * 8;
#pragma unroll
    for (int j = 0; j < 8; ++j) WihHi[g][j] = f2bf(q[j]);
    float bi = bih[n], bh = bhh[n];
    if (g == 0) { float v = bi + bh; bias_r  = (f32x4){v, v, v, v}; }
    if (g == 1) { float v = bi + bh; bias_z  = (f32x4){v, v, v, v}; }
    if (g == 2) { bias_xn = (f32x4){bi, bi, bi, bi};
                  bias_hn = (f32x4){bh, bh, bh, bh}; }
  }

  // conv2 role: wave w -> stream cq = w>>1, channel-tile cnt = w&1
  const int cq  = wv >> 1;
  const int cnt = wv & 1;
  s16x8 cW2[2];
  f32x4 b2v4;
  {
    const int ch = 16 * cnt + l15;
    float bv = b2[ch];
    b2v4 = (f32x4){bv, bv, bv, bv};
#pragma unroll
    for (int ks = 0; ks < 2; ++ks) {
      s16x8 h8;
#pragma unroll
      for (int j = 0; j < 8; ++j) {
        const int k = ks * 32 + lg * 8 + j;
        const int g = k >> 4, ii = k & 15;
        h8[j] = (g < 3) ? f2bf(w2[ch * 48 + ii * 3 + g]) : (short)0;
      }
      cW2[ks] = h8;
    }
  }

  // conv1: thread -> (seq sl, ch chc) for BOTH streams (A=S0, B=S1)
  const int sl  = tid >> 4;       // 0..15
  const int chc = tid & 15;
  const float w1v0 = w1[chc * 3 + 0], w1v1 = w1[chc * 3 + 1], w1v2 = w1[chc * 3 + 2];
  const float b1v = b1[chc];

  // ---- hoisted LDS pointers ----
  const int i0a = (lg & 1) * 8;
  const int grp = lg >> 1;
  const short* ringRdC = &ring[cq][0][0] + l15 * 24 + i0a;   // conv2 reads
  int sA0off[4], sA1off[4];
#pragma unroll
  for (int p = 0; p < 4; ++p) {
    sA0off[p] = ((p + 3 + grp) & 3) * 384;
    sA1off[p] = ((p + 1 + grp) & 3) * 384;
  }
  const short* sRd0 = &s_s[0][0][0] + l15 * 40 + lg * 8;
  const short* sRd1 = &s_s[1][0][0] + l15 * 40 + lg * 8;
  const short* hRd0 = &hA[0][0][0] + l15 * 72 + lg * 8;
  const short* hRd1 = &hA[1][0][0] + l15 * 72 + lg * 8;
  short* hWr0 = &hA[0][0][0] + (lg * 4) * 72 + 16 * wv + l15;
  short* hWr1 = &hA[1][0][0] + (lg * 4) * 72 + 16 * wv + l15;
  short* swWr = &s_s[cq][0][0] + (lg * 4) * 40 + cnt * 16 + l15;
  short* rwA  = &ring[0][0][0] + sl * 24 + chc;
  short* rwB  = &ring[1][0][0] + sl * 24 + chc;
  const float* xpA = &x_s[sl * T];
  const float* xpB = &x_s[(sl + 16) * T];

  __syncthreads();

#define CONV2_STEP(P_, WB_) do {                                              \
    s16x8 a0 = *reinterpret_cast<const s16x8*>(ringRdC + sA0off[(P_)]);       \
    s16x8 a1 = *reinterpret_cast<const s16x8*>(ringRdC + sA1off[(P_)]);       \
    f32x4 sa = MFMA16(a1, cW2[1], MFMA16(a0, cW2[0], b2v4));                  \
    float m0 = sa[0] > 0.f ? sa[0] : 0.f;                                     \
    float m1 = sa[1] > 0.f ? sa[1] : 0.f;                                     \
    float m2 = sa[2] > 0.f ? sa[2] : 0.f;                                     \
    float m3 = sa[3] > 0.f ? sa[3] : 0.f;                                     \
    uint32_t u01, u23;                                                        \
    asm("v_cvt_pk_bf16_f32 %0, %1, %2" : "=v"(u01) : "v"(m0), "v"(m1));       \
    asm("v_cvt_pk_bf16_f32 %0, %1, %2" : "=v"(u23) : "v"(m2), "v"(m3));       \
    swWr[(WB_) * 640 +   0] = (short)(u01 & 0xffff);                          \
    swWr[(WB_) * 640 +  40] = (short)(u01 >> 16);                             \
    swWr[(WB_) * 640 +  80] = (short)(u23 & 0xffff);                          \
    swWr[(WB_) * 640 + 120] = (short)(u23 >> 16);                             \
  } while (0)

  // ---- prologue: c1(0) both streams -> sync -> s(0) all waves & c1(1) -> sync
  float xaA = xpA[0], xbA = xpA[1];
  float xaB = xpB[0], xbB = xpB[1];
  {
    float cA = b1v + w1v2 * xaA; cA = cA > 0.f ? cA : 0.f;
    float cB = b1v + w1v2 * xaB; cB = cB > 0.f ? cB : 0.f;
    uint32_t cu;
    asm("v_cvt_pk_bf16_f32 %0, %1, %2" : "=v"(cu) : "v"(cA), "v"(cB));
    rwA[0] = (short)(cu & 0xffff);
    rwB[0] = (short)(cu >> 16);
  }
  __syncthreads();
  CONV2_STEP(3, 0);   // u=0 -> phase-3 slot pattern; all 4 waves (both streams)
  {
    float cA = b1v + w1v1 * xaA + w1v2 * xbA; cA = cA > 0.f ? cA : 0.f;
    float cB = b1v + w1v1 * xaB + w1v2 * xbB; cB = cB > 0.f ? cB : 0.f;
    uint32_t cu;
    asm("v_cvt_pk_bf16_f32 %0, %1, %2" : "=v"(cu) : "v"(cA), "v"(cB));
    rwA[384] = (short)(cu & 0xffff);
    rwB[384] = (short)(cu >> 16);
  }
  __syncthreads();

  float hreg0[4] = {0.f, 0.f, 0.f, 0.f};
  float hreg1[4] = {0.f, 0.f, 0.f, 0.f};

#define GRU_STEP(T_, P_, C2_, C1_) do {                                       \
    const int rb_ = (P_) & 1, wb_ = rb_ ^ 1;                                  \
    s16x8 as0  = *reinterpret_cast<const s16x8*>(sRd0 + rb_ * 640);           \
    s16x8 ah00 = *reinterpret_cast<const s16x8*>(hRd0 + rb_ * 1152);          \
    s16x8 ah01 = *reinterpret_cast<const s16x8*>(hRd0 + rb_ * 1152 + 32);     \
    s16x8 as1  = *reinterpret_cast<const s16x8*>(sRd1 + rb_ * 640);           \
    s16x8 ah10 = *reinterpret_cast<const s16x8*>(hRd1 + rb_ * 1152);          \
    s16x8 ah11 = *reinterpret_cast<const s16x8*>(hRd1 + rb_ * 1152 + 32);     \
    f32x4 pr0 = MFMA16(as0, WihHi[0],                                         \
                MFMA16(ah01, WhhHi[0][1],                                     \
                MFMA16(ah00, WhhHi[0][0], bias_r)));                          \
    f32x4 pz0 = MFMA16(as0, WihHi[1],                                         \
                MFMA16(ah01, WhhHi[1][1],                                     \
                MFMA16(ah00, WhhHi[1][0], bias_z)));                          \
    f32x4 xn0 = MFMA16(as0, WihHi[2], bias_xn);                               \
    f32x4 hn0 = MFMA16(ah01, WhhHi[2][1],                                     \
                MFMA16(ah00, WhhHi[2][0], bias_hn));                          \
    f32x4 pr1 = MFMA16(as1, WihHi[0],                                         \
                MFMA16(ah11, WhhHi[0][1],                                     \
                MFMA16(ah10, WhhHi[0][0], bias_r)));                          \
    f32x4 pz1 = MFMA16(as1, WihHi[1],                                         \
                MFMA16(ah11, WhhHi[1][1],                                     \
                MFMA16(ah10, WhhHi[1][0], bias_z)));                          \
    f32x4 xn1 = MFMA16(as1, WihHi[2], bias_xn);                               \
    f32x4 hn1 = MFMA16(ah11, WhhHi[2][1],                                     \
                MFMA16(ah10, WhhHi[2][0], bias_hn));                          \
    if (C2_) { CONV2_STEP((P_), wb_); }                                       \
    if (C1_) {                                                                \
      float xcA = xpA[(T_) + 2], xcB = xpB[(T_) + 2];                         \
      float cA = b1v + w1v0 * xaA + w1v1 * xbA + w1v2 * xcA;                  \
      cA = cA > 0.f ? cA : 0.f;                                               \
      float cB = b1v + w1v0 * xaB + w1v1 * xbB + w1v2 * xcB;                  \
      cB = cB > 0.f ? cB : 0.f;                                               \
      uint32_t cu_;                                                           \
      asm("v_cvt_pk_bf16_f32 %0, %1, %2" : "=v"(cu_) : "v"(cA), "v"(cB));     \
      rwA[(((P_) + 2) & 3) * 384] = (short)(cu_ & 0xffff);                    \
      rwB[(((P_) + 2) & 3) * 384] = (short)(cu_ >> 16);                       \
      xaA = xbA; xbA = xcA; xaB = xbB; xbB = xcB;                             \
    }                                                                         \
    float h0n[4], h1n[4];                                                     \
    _Pragma("unroll")                                                         \
    for (int i2 = 0; i2 < 4; ++i2) {                                          \
      float r = sigm_fast(pr0[i2]);                                           \
      float z = sigm_fast(pz0[i2]);                                           \
      float tn = tanh_fast(__builtin_fmaf(r, hn0[i2], xn0[i2]));              \
      float h = __builtin_fmaf(z, hreg0[i2] - tn, tn);                        \
      hreg0[i2] = h; h0n[i2] = h;                                             \
    }                                                                         \
    _Pragma("unroll")                                                         \
    for (int i2 = 0; i2 < 4; ++i2) {                                          \
      float r = sigm_fast(pr1[i2]);                                           \
      float z = sigm_fast(pz1[i2]);                                           \
      float tn = tanh_fast(__builtin_fmaf(r, hn1[i2], xn1[i2]));              \
      float h = __builtin_fmaf(z, hreg1[i2] - tn, tn);                        \
      hreg1[i2] = h; h1n[i2] = h;                                             \
    }                                                                         \
    uint32_t a01, a23, b01, b23;                                              \
    asm("v_cvt_pk_bf16_f32 %0, %1, %2" : "=v"(a01) : "v"(h0n[0]), "v"(h0n[1])); \
    asm("v_cvt_pk_bf16_f32 %0, %1, %2" : "=v"(a23) : "v"(h0n[2]), "v"(h0n[3])); \
    asm("v_cvt_pk_bf16_f32 %0, %1, %2" : "=v"(b01) : "v"(h1n[0]), "v"(h1n[1])); \
    asm("v_cvt_pk_bf16_f32 %0, %1, %2" : "=v"(b23) : "v"(h1n[2]), "v"(h1n[3])); \
    hWr0[wb_ * 1152 +   0] = (short)(a01 & 0xffff);                           \
    hWr0[wb_ * 1152 +  72] = (short)(a01 >> 16);                              \
    hWr0[wb_ * 1152 + 144] = (short)(a23 & 0xffff);                           \
    hWr0[wb_ * 1152 + 216] = (short)(a23 >> 16);                              \
    hWr1[wb_ * 1152 +   0] = (short)(b01 & 0xffff);                           \
    hWr1[wb_ * 1152 +  72] = (short)(b01 >> 16);                              \
    hWr1[wb_ * 1152 + 144] = (short)(b23 & 0xffff);                           \
    hWr1[wb_ * 1152 + 216] = (short)(b23 >> 16);                              \
    __syncthreads();                                                          \
  } while (0)

#pragma unroll 1
  for (int t = 0; t < 96; t += 4) {
    GRU_STEP(t + 0, 0, true, true);
    GRU_STEP(t + 1, 1, true, true);
    GRU_STEP(t + 2, 2, true, true);
    GRU_STEP(t + 3, 3, true, true);
  }
  GRU_STEP(96, 0, true, true);
  GRU_STEP(97, 1, true, true);
  GRU_STEP(98, 2, true, false);
  GRU_STEP(99, 3, false, false);

#pragma unroll
  for (int i2 = 0; i2 < 4; ++i2) {
    out[(size_t)(seq0 + lg * 4 + i2) * 64 + 16 * wv + l15] = hreg0[i2];
    out[(size_t)(seq0 + 16 + lg * 4 + i2) * 64 + 16 * wv + l15] = hreg1[i2];
  }
}

extern "C" void kernel_launch(void* const* d_in, const int* in_sizes, int n_in,
                              void* d_out, int out_size, void* d_ws, size_t ws_size,
                              hipStream_t stream)
{
  (void)in_sizes; (void)n_in; (void)d_ws; (void)ws_size; (void)out_size;
  const float* x   = (const float*)d_in[0];
  const float* w1  = (const float*)d_in[1];
  const float* b1  = (const float*)d_in[2];
  const float* w2  = (const float*)d_in[3];
  const float* b2  = (const float*)d_in[4];
  const float* Wih = (const float*)d_in[5];
  const float* Whh = (const float*)d_in[6];
  const float* bih = (const float*)d_in[7];
  const float* bhh = (const float*)d_in[8];
  float* out = (float*)d_out;
  te_fused<<<256, 256, 0, stream>>>(x, w1, b1, w2, b2, Wih, Whh, bih, bhh, out);
}

// Round 8
// 74.640 us; speedup vs baseline: 1.1724x; 1.1724x over previous
//
#include <hip/hip_runtime.h>
#include <stdint.h>

typedef __attribute__((ext_vector_type(8))) short s16x8;
typedef __attribute__((ext_vector_type(4))) float f32x4;

__device__ __forceinline__ short f2bf(float f){
  union { float f; uint32_t u; } v; v.f = f;
  uint32_t u = v.u;
  u += 0x7fffu + ((u >> 16) & 1u);
  return (short)(u >> 16);
}
__device__ __forceinline__ float sigm_fast(float x){
  float e = __builtin_amdgcn_exp2f(x * -1.44269504f);
  return __builtin_amdgcn_rcpf(1.f + e);
}
__device__ __forceinline__ float tanh_fast(float x){
  float e = __builtin_amdgcn_exp2f(x * 2.88539008f);
  return __builtin_fmaf(-2.f, __builtin_amdgcn_rcpf(e + 1.f), 1.f);
}

#define MFMA16(a, b, c) __builtin_amdgcn_mfma_f32_16x16x32_bf16((a), (b), (c), 0, 0, 0)

// Fused TemporalEncoder. Round-8 structure: back to M=16/grid=512 (2 blocks/CU,
// 2 waves/SIMD -- measured sweet spot, r7 showed 1 wave/SIMD convoys). Convs are
// EVICTED from the per-step loop: per 16-step chunk, a batched phase computes
// conv1 (19 taus, flat sliding-window buffer, no ring) and conv2 (16 timesteps,
// 8 MFMA-tasks/wave) into LDS; the GRU inner loop is fully unrolled and
// branch-free (immediate LDS offsets, 9 MFMA, elementwise, barrier). Numerics
// identical to round 6 (absmax must stay ~1.95e-3).
__global__ __launch_bounds__(256, 2) void te_fused(
    const float* __restrict__ x,
    const float* __restrict__ w1, const float* __restrict__ b1,
    const float* __restrict__ w2, const float* __restrict__ b2,
    const float* __restrict__ Wih, const float* __restrict__ Whh,
    const float* __restrict__ bih, const float* __restrict__ bhh,
    float* __restrict__ out)
{
  __shared__ float x_s[16 * 100];     // staged input rows (6400 B)
  __shared__ short hA[2][16 * 72];    // [buf][seq][72-pad dim] bf16 h (4608 B)
  __shared__ short c1b[16 * 328];     // [seq][19+ tau][16 ch], 328-pad (10496 B)
  __shared__ short s_b[16 * 640];     // [16 t][16 seq][40-pad ch(32)] (20480 B)

  const int tid  = threadIdx.x;
  const int lane = tid & 63;
  const int wv   = tid >> 6;
  const int l15  = lane & 15;
  const int lg   = lane >> 4;
  const int seq0 = blockIdx.x * 16;

  // ---- stage x ----
  {
    const float4* gx = reinterpret_cast<const float4*>(x + (size_t)seq0 * 100);
    float4* sx = reinterpret_cast<float4*>(x_s);
    for (int i = tid; i < 400; i += 256) sx[i] = gx[i];
  }
  // zero h buf0
  {
    int* p = reinterpret_cast<int*>(&hA[0][0]);
    for (int i = tid; i < 576; i += 256) p[i] = 0;
  }

  // ---- weight B-fragments (same as round 6) ----
  s16x8 WhhHi[3][2], WihHi[3];
  f32x4 bias_r, bias_z, bias_xn, bias_hn;
#pragma unroll
  for (int g = 0; g < 3; ++g) {
    const int n = 64 * g + 16 * wv + l15;
#pragma unroll
    for (int ks = 0; ks < 2; ++ks) {
      const float* p = Whh + n * 64 + ks * 32 + lg * 8;
#pragma unroll
      for (int j = 0; j < 8; ++j) WhhHi[g][ks][j] = f2bf(p[j]);
    }
    const float* q = Wih + n * 32 + lg * 8;
#pragma unroll
    for (int j = 0; j < 8; ++j) WihHi[g][j] = f2bf(q[j]);
    float bi = bih[n], bh = bhh[n];
    if (g == 0) { float v = bi + bh; bias_r  = (f32x4){v, v, v, v}; }
    if (g == 1) { float v = bi + bh; bias_z  = (f32x4){v, v, v, v}; }
    if (g == 2) { bias_xn = (f32x4){bi, bi, bi, bi};
                  bias_hn = (f32x4){bh, bh, bh, bh}; }
  }

  // conv2 B-frags: flat k = ks*32+lg*8+j, group g=k>>4: g<3 -> tap g, g==3 -> 0.
  s16x8 cW2[2];
  f32x4 b2v4;
  {
    const int ch = 16 * (wv & 1) + l15;
    float bv = b2[ch];
    b2v4 = (f32x4){bv, bv, bv, bv};
#pragma unroll
    for (int ks = 0; ks < 2; ++ks) {
      s16x8 h8;
#pragma unroll
      for (int j = 0; j < 8; ++j) {
        const int k = ks * 32 + lg * 8 + j;
        const int g = k >> 4, ii = k & 15;
        h8[j] = (g < 3) ? f2bf(w2[ch * 48 + ii * 3 + g]) : (short)0;
      }
      cW2[ks] = h8;
    }
  }

  // conv1 mapping: all 256 threads, (seq, ch)
  const int sl  = tid >> 4;
  const int chc = tid & 15;
  const float w1v0 = w1[chc * 3 + 0], w1v1 = w1[chc * 3 + 1], w1v2 = w1[chc * 3 + 2];
  const float b1v = b1[chc];

  // ---- hoisted LDS pointers ----
  const short* sRd  = &s_b[0]   + l15 * 40 + lg * 8;       // GRU s A-frag
  const short* hRd  = &hA[0][0] + l15 * 72 + lg * 8;       // GRU h A-frag
  short*       hWr  = &hA[0][0] + (lg * 4) * 72 + 16 * wv + l15;
  const short* c1Rd = &c1b[0]   + l15 * 328 + lg * 8;      // conv2 A-frag base
  short*       sWr  = &s_b[0]   + (lg * 4) * 40 + (wv & 1) * 16 + l15;
  short*       c1Wr = &c1b[0]   + sl * 328 + chc;
  const float* xRd  = &x_s[sl * 100];
  const int    ub   = (wv >> 1) * 8;                        // conv2 u-range base

  __syncthreads();

  float hreg[4] = {0.f, 0.f, 0.f, 0.f};

#define GSTEP(TL) do {                                                        \
    const int rb_ = (TL) & 1, wb_ = rb_ ^ 1;                                  \
    s16x8 as_ = *reinterpret_cast<const s16x8*>(sRd + (TL) * 640);            \
    s16x8 ah0 = *reinterpret_cast<const s16x8*>(hRd + rb_ * 1152);            \
    s16x8 ah1 = *reinterpret_cast<const s16x8*>(hRd + rb_ * 1152 + 32);       \
    __builtin_amdgcn_s_setprio(1);                                            \
    f32x4 pr = MFMA16(as_, WihHi[0],                                          \
               MFMA16(ah1, WhhHi[0][1],                                       \
               MFMA16(ah0, WhhHi[0][0], bias_r)));                            \
    f32x4 pz = MFMA16(as_, WihHi[1],                                          \
               MFMA16(ah1, WhhHi[1][1],                                       \
               MFMA16(ah0, WhhHi[1][0], bias_z)));                            \
    f32x4 xn = MFMA16(as_, WihHi[2], bias_xn);                                \
    f32x4 hn = MFMA16(ah1, WhhHi[2][1],                                       \
               MFMA16(ah0, WhhHi[2][0], bias_hn));                            \
    __builtin_amdgcn_s_setprio(0);                                            \
    float hnew[4];                                                            \
    _Pragma("unroll")                                                         \
    for (int i2 = 0; i2 < 4; ++i2) {                                          \
      float r = sigm_fast(pr[i2]);                                            \
      float z = sigm_fast(pz[i2]);                                            \
      float tn = tanh_fast(__builtin_fmaf(r, hn[i2], xn[i2]));                \
      float h = __builtin_fmaf(z, hreg[i2] - tn, tn);                         \
      hreg[i2] = h; hnew[i2] = h;                                             \
    }                                                                         \
    uint32_t p01, p23;                                                        \
    asm("v_cvt_pk_bf16_f32 %0, %1, %2" : "=v"(p01) : "v"(hnew[0]), "v"(hnew[1])); \
    asm("v_cvt_pk_bf16_f32 %0, %1, %2" : "=v"(p23) : "v"(hnew[2]), "v"(hnew[3])); \
    hWr[wb_ * 1152 +   0] = (short)(p01 & 0xffff);                            \
    hWr[wb_ * 1152 +  72] = (short)(p01 >> 16);                               \
    hWr[wb_ * 1152 + 144] = (short)(p23 & 0xffff);                            \
    hWr[wb_ * 1152 + 216] = (short)(p23 >> 16);                               \
    __syncthreads();                                                          \
  } while (0)

#pragma unroll 1
  for (int k = 0; k < 7; ++k) {
    const int t0 = k * 16;

    // ---- phase: conv1 for taus t0-2 .. t0+16 (19 slots, flat layout) ----
    {
      int xi0 = t0 - 4, xi1 = t0 - 3;
      float xa = (xi0 < 0) ? 0.f : xRd[xi0 < 0 ? 0 : xi0];
      float xb = (xi1 < 0) ? 0.f : xRd[xi1 < 0 ? 0 : xi1];
#pragma unroll
      for (int i = 0; i < 19; ++i) {
        const int xi = t0 - 2 + i;
        const int idx = xi < 0 ? 0 : (xi > 99 ? 99 : xi);
        float xv = xRd[idx];
        float xc = (xi < 0) ? 0.f : xv;              // keep rolling regs clean
        float c = __builtin_fmaf(w1v0, xa,
                  __builtin_fmaf(w1v1, xb,
                  __builtin_fmaf(w1v2, xc, b1v)));
        c = c > 0.f ? c : 0.f;
        c = (xi < 0) ? 0.f : c;                      // conv2 causal pad: c1(<0)=0
        uint32_t cu;
        asm("v_cvt_pk_bf16_f32 %0, %1, %2" : "=v"(cu) : "v"(c), "v"(c));
        c1Wr[i * 16] = (short)(cu & 0xffff);
        xa = xb; xb = xc;
      }
    }
    __syncthreads();

    // ---- phase: conv2 for 16 local timesteps (8 MFMA-tasks per wave) ----
    {
#pragma unroll
      for (int i = 0; i < 8; ++i) {
        const int u = ub + i;                        // local timestep 0..15
        s16x8 a0 = *reinterpret_cast<const s16x8*>(c1Rd + u * 16);
        s16x8 a1 = *reinterpret_cast<const s16x8*>(c1Rd + u * 16 + 32);
        f32x4 sa = MFMA16(a1, cW2[1], MFMA16(a0, cW2[0], b2v4));
        float m0 = sa[0] > 0.f ? sa[0] : 0.f;
        float m1 = sa[1] > 0.f ? sa[1] : 0.f;
        float m2 = sa[2] > 0.f ? sa[2] : 0.f;
        float m3 = sa[3] > 0.f ? sa[3] : 0.f;
        uint32_t u01, u23;
        asm("v_cvt_pk_bf16_f32 %0, %1, %2" : "=v"(u01) : "v"(m0), "v"(m1));
        asm("v_cvt_pk_bf16_f32 %0, %1, %2" : "=v"(u23) : "v"(m2), "v"(m3));
        sWr[u * 640 +   0] = (short)(u01 & 0xffff);
        sWr[u * 640 +  40] = (short)(u01 >> 16);
        sWr[u * 640 +  80] = (short)(u23 & 0xffff);
        sWr[u * 640 + 120] = (short)(u23 >> 16);
      }
    }
    __syncthreads();

    // ---- lean GRU steps (branch-free, fully unrolled) ----
    if (k < 6) {
      GSTEP(0);  GSTEP(1);  GSTEP(2);  GSTEP(3);
      GSTEP(4);  GSTEP(5);  GSTEP(6);  GSTEP(7);
      GSTEP(8);  GSTEP(9);  GSTEP(10); GSTEP(11);
      GSTEP(12); GSTEP(13); GSTEP(14); GSTEP(15);
    } else {
      GSTEP(0);  GSTEP(1);  GSTEP(2);  GSTEP(3);   // steps 96..99
    }
  }

#pragma unroll
  for (int i2 = 0; i2 < 4; ++i2) {
    out[(size_t)(seq0 + lg * 4 + i2) * 64 + 16 * wv + l15] = hreg[i2];
  }
}

extern "C" void kernel_launch(void* const* d_in, const int* in_sizes, int n_in,
                              void* d_out, int out_size, void* d_ws, size_t ws_size,
                              hipStream_t stream)
{
  (void)in_sizes; (void)n_in; (void)d_ws; (void)ws_size; (void)out_size;
  const float* x   = (const float*)d_in[0];
  const float* w1  = (const float*)d_in[1];
  const float* b1  = (const float*)d_in[2];
  const float* w2  = (const float*)d_in[3];
  const float* b2  = (const float*)d_in[4];
  const float* Wih = (const float*)d_in[5];
  const float* Whh = (const float*)d_in[6];
  const float* bih = (const float*)d_in[7];
  const float* bhh = (const float*)d_in[8];
  float* out = (float*)d_out;
  te_fused<<<512, 256, 0, stream>>>(x, w1, b1, w2, b2, Wih, Whh, bih, bhh, out);
}